// Round 2
// baseline (246.870 us; speedup 1.0000x reference)
//
#include <hip/hip_runtime.h>
#include <hip/hip_bf16.h>
#include <math.h>

#define S 4096
#define CIN 256
#define C3 768
#define NH 8
#define HD 32
#define KSPLIT 4

static constexpr float EPS = 1e-4f;

typedef __attribute__((ext_vector_type(8))) __bf16 bf16x8;
typedef __attribute__((ext_vector_type(4))) float f32x4;
typedef __attribute__((ext_vector_type(16))) float f32x16;
typedef __attribute__((ext_vector_type(8))) unsigned short u16x8;
typedef __attribute__((ext_vector_type(4))) unsigned u32x4;

static inline __device__ ushort f2bf(float f) {  // RN-even
  unsigned u = __float_as_uint(f);
  return (ushort)((u + 0x7fffu + ((u >> 16) & 1u)) >> 16);
}

// v_cvt_pk_bf16_f32: dst.lo16 = bf16(lo), dst.hi16 = bf16(hi); RNE (no builtin)
static inline __device__ unsigned cvt_pk_bf16(float lo, float hi) {
  unsigned r;
  asm("v_cvt_pk_bf16_f32 %0, %1, %2" : "=v"(r) : "v"(lo), "v"(hi));
  return r;
}
// v_permlane32_swap_b32: a.hi32lanes <-> b.lo32lanes.
static inline __device__ void plane32_swap(unsigned& a, unsigned& b) {
  asm("v_permlane32_swap_b32 %0, %1" : "+v"(a), "+v"(b));
}

#define EXP2 __builtin_amdgcn_exp2f

// Convert one 32x32 QK score tile (D-layout: col=q=lane&31, row=k=(r&3)+8*(r>>2)+4*hi)
// to two PV operand fragments (col/row=q, k = frag*8 elements at 8*hi+j) fully
// in registers: 8 cvt_pk + 4 permlane32_swap. plo covers k 0..15, phi 16..31.
// Also accumulates this lane's sum of the 16 exp values into lacc (softmax
// denominator; replaces the ones-MFMA -- saves 4 MFMAs/iter and 16 VGPRs).
static inline __device__ void s_to_pf(const f32x16 s, bf16x8& plo, bf16x8& phi,
                                      float& lacc) {
  float e[16];
  #pragma unroll
  for (int i = 0; i < 16; i++) e[i] = EXP2(s[i]);
  lacc += ((((e[0] + e[1]) + (e[2] + e[3])) + ((e[4] + e[5]) + (e[6] + e[7]))) +
           (((e[8] + e[9]) + (e[10] + e[11])) + ((e[12] + e[13]) + (e[14] + e[15]))));
  unsigned c0 = cvt_pk_bf16(e[0], e[1]);    // hi0:k(0,1)   hi1:k(4,5)
  unsigned c1 = cvt_pk_bf16(e[2], e[3]);    // hi0:k(2,3)   hi1:k(6,7)
  unsigned c2 = cvt_pk_bf16(e[4], e[5]);    // hi0:k(8,9)   hi1:k(12,13)
  unsigned c3 = cvt_pk_bf16(e[6], e[7]);    // hi0:k(10,11) hi1:k(14,15)
  plane32_swap(c0, c2);
  plane32_swap(c1, c3);
  u32x4 lo4 = {c0, c1, c2, c3};
  plo = __builtin_bit_cast(bf16x8, lo4);
  unsigned c4 = cvt_pk_bf16(e[8], e[9]);
  unsigned c5 = cvt_pk_bf16(e[10], e[11]);
  unsigned c6 = cvt_pk_bf16(e[12], e[13]);
  unsigned c7 = cvt_pk_bf16(e[14], e[15]);
  plane32_swap(c4, c6);
  plane32_swap(c5, c7);
  u32x4 hi4 = {c4, c5, c6, c7};
  phi = __builtin_bit_cast(bf16x8, hi4);
}

// ---------------- weight norm (both weights, one launch) ---------------------
__global__ __launch_bounds__(256) void wnorm_kernel(const float* __restrict__ w_qkv,
                                                    const float* __restrict__ w_out,
                                                    ushort* __restrict__ wqb,
                                                    ushort* __restrict__ wob) {
  const int row = blockIdx.x * 4 + (threadIdx.x >> 6);
  const int lane = threadIdx.x & 63;
  const bool is_q = row < C3;
  const float* wr = (is_q ? w_qkv + (size_t)row * CIN : w_out + (size_t)(row - C3) * CIN);
  float v0 = wr[lane], v1 = wr[lane + 64], v2 = wr[lane + 128], v3 = wr[lane + 192];
  float ss = v0 * v0 + v1 * v1 + v2 * v2 + v3 * v3;
  #pragma unroll
  for (int off = 32; off > 0; off >>= 1) ss += __shfl_down(ss, off, 64);
  ss = __shfl(ss, 0, 64);
  const float scale = 1.0f / (sqrtf(ss) + 16.0f * EPS);
  ushort* whr = (is_q ? wqb + (size_t)row * CIN : wob + (size_t)(row - C3) * CIN);
  whr[lane] = f2bf(v0 * scale);
  whr[lane + 64] = f2bf(v1 * scale);
  whr[lane + 128] = f2bf(v2 * scale);
  whr[lane + 192] = f2bf(v3 * scale);
}

// ---------------- X [b][c][s] fp32 -> Xt [b][s][c] bf16 ----------------------
__global__ __launch_bounds__(256) void xt_kernel(const float* __restrict__ X,
                                                 ushort* __restrict__ Xt) {
  const int b = blockIdx.z;
  const int s0 = blockIdx.x * 64, c0 = blockIdx.y * 64;
  __shared__ ushort T[64][72];
  const int tc = threadIdx.x >> 4;
  const int ts = threadIdx.x & 15;
  #pragma unroll
  for (int i = 0; i < 4; i++) {
    const float4 v = *(const float4*)&X[((size_t)(b * CIN + c0 + tc + 16 * i)) * S + s0 + ts * 4];
    ushort4 u;
    u.x = f2bf(v.x); u.y = f2bf(v.y); u.z = f2bf(v.z); u.w = f2bf(v.w);
    *(ushort4*)&T[tc + 16 * i][ts * 4] = u;
  }
  __syncthreads();
  #pragma unroll
  for (int i = 0; i < 4; i++) {
    const int sr = tc + 16 * i;
    ushort4 u;
    u.x = T[ts * 4 + 0][sr];
    u.y = T[ts * 4 + 1][sr];
    u.z = T[ts * 4 + 2][sr];
    u.w = T[ts * 4 + 3][sr];
    *(ushort4*)&Xt[((size_t)b * S + s0 + sr) * CIN + c0 + ts * 4] = u;
  }
}

// ---------------- conv1 fused with pixel-norm + layout fan-out ---------------
__global__ __launch_bounds__(256) void conv1_fused_kernel(const ushort* __restrict__ W,
                                                          const ushort* __restrict__ Bm,
                                                          ushort* __restrict__ Qn,
                                                          ushort* __restrict__ Kn,
                                                          ushort* __restrict__ Vt) {
  const int b = blockIdx.z;
  const int wid = threadIdx.x >> 6, lane = threadIdx.x & 63;
  const int col = lane & 15, quad = lane >> 4;
  const int m0 = blockIdx.y * 64 + (wid >> 1) * 32;  // 32-aligned: one head group
  const int n0 = blockIdx.x * 128 + (wid & 1) * 64;
  const ushort* Bb = Bm + (size_t)b * S * CIN;
  f32x4 acc[2][4] = {};
  #pragma unroll
  for (int k0 = 0; k0 < CIN; k0 += 32) {
    bf16x8 af[2], bf[4];
    #pragma unroll
    for (int mi = 0; mi < 2; mi++)
      af[mi] = *(const bf16x8*)&W[(size_t)(m0 + mi * 16 + col) * CIN + k0 + quad * 8];
    #pragma unroll
    for (int ni = 0; ni < 4; ni++)
      bf[ni] = *(const bf16x8*)&Bb[(size_t)(n0 + ni * 16 + col) * CIN + k0 + quad * 8];
    #pragma unroll
    for (int mi = 0; mi < 2; mi++)
      #pragma unroll
      for (int ni = 0; ni < 4; ni++)
        acc[mi][ni] = __builtin_amdgcn_mfma_f32_16x16x32_bf16(af[mi], bf[ni], acc[mi][ni], 0, 0, 0);
  }

  const int g = m0 >> 5;   // 0..23: group; 0-7 Q, 8-15 K, 16-23 V
  const int h = g & 7;
  float rn[4];
  #pragma unroll
  for (int ni = 0; ni < 4; ni++) {
    float ss = 0.f;
    #pragma unroll
    for (int mi = 0; mi < 2; mi++)
      #pragma unroll
      for (int r = 0; r < 4; r++) ss += acc[mi][ni][r] * acc[mi][ni][r];
    ss += __shfl_xor(ss, 16, 64);
    ss += __shfl_xor(ss, 32, 64);
    rn[ni] = rsqrtf(ss * (1.0f / HD) + EPS);
    if (g < 8) rn[ni] *= 0.2550348190698169f;  // log2(e)/sqrt(32) folded into Q
  }

  if (g < 16) {
    ushort* dst = (g < 8 ? Qn : Kn) + (size_t)(b * NH + h) * S * HD;
    #pragma unroll
    for (int mi = 0; mi < 2; mi++)
      #pragma unroll
      for (int ni = 0; ni < 4; ni++) {
        ushort4 u;
        u.x = f2bf(acc[mi][ni][0] * rn[ni]);
        u.y = f2bf(acc[mi][ni][1] * rn[ni]);
        u.z = f2bf(acc[mi][ni][2] * rn[ni]);
        u.w = f2bf(acc[mi][ni][3] * rn[ni]);
        *(ushort4*)&dst[(size_t)(n0 + ni * 16 + col) * HD + mi * 16 + quad * 4] = u;
      }
  } else {
    ushort* dst = Vt + (size_t)(b * NH + h) * HD * S;
    #pragma unroll
    for (int mi = 0; mi < 2; mi++)
      #pragma unroll
      for (int ni = 0; ni < 4; ni++)
        #pragma unroll
        for (int r = 0; r < 4; r++)
          dst[(size_t)(mi * 16 + quad * 4 + r) * S + n0 + ni * 16 + col] =
              f2bf(acc[mi][ni][r] * rn[ni]);
  }
}

// ---------------- MFMA attention: 32x32 tiles, P in registers ----------------
// S^T = K.Q^T via mfma_32x32x16 (Q pre-scaled -> exp2 direct). P rebuilt into
// the PV operand fragment in registers (T12); l = f32 sum of exps (no MFMA).
// KSPLIT=4 -> 2048 blocks = 8 blocks/CU (full occupancy, 2x MLP).
// XCD-bijective swizzle: each XCD hosts 8 complete (b,kp,h) groups so its K/V
// working set is 8 x 128 KB = 1 MB (L2-resident) instead of thrashing.
// grid 2048 x 256 (4 waves), zero LDS.
__global__ __launch_bounds__(256, 8) void attn_kernel(const ushort* __restrict__ Qn,
                                                      const ushort* __restrict__ Kn,
                                                      const ushort* __restrict__ Vt,
                                                      float* __restrict__ accP,
                                                      float* __restrict__ lP) {
  // bijective XCD swizzle (nwg = 2048, 8 XCDs, 256 blocks/XCD):
  // hardware assigns bid -> XCD (bid & 7); give that XCD consecutive ids.
  const int bid = blockIdx.x;
  const int id = (bid & 7) * (2048 / 8) + (bid >> 3);
  const int qt = id & 31;       // q-tile within group
  const int grp = id >> 5;      // 0..63 = ((b*KSPLIT + kp) << 3) | h
  const int h = grp & 7;
  const int kp = (grp >> 3) & (KSPLIT - 1);
  const int b = grp >> 5;       // KSPLIT==4
  const int wid = threadIdx.x >> 6, lane = threadIdx.x & 63;
  const int ln = lane & 31, hi = lane >> 5;
  const int q0 = qt * 128 + wid * 32;

  const ushort* Qh = Qn + (size_t)(b * NH + h) * S * HD;
  const ushort* Kh = Kn + (size_t)(b * NH + h) * S * HD;
  const ushort* Vh = Vt + (size_t)(b * NH + h) * HD * S;

  // Q as B-frag: col=q=ln, ch = half*16 + 8*hi + j
  bf16x8 qf0 = *(const bf16x8*)&Qh[(size_t)(q0 + ln) * HD + hi * 8];
  bf16x8 qf1 = *(const bf16x8*)&Qh[(size_t)(q0 + ln) * HD + 16 + hi * 8];

  const f32x16 z = {};
  f32x16 acc = {};   // out^T tile: row=d, col=q
  float lacc = 0.f;  // per-lane softmax denom partial

  const int kt0 = kp * (S / KSPLIT);
  // K as A-frag: row=key=ln, ch = 8*hi + j (+16 for second ch half)
  const ushort* Kp = Kh + (size_t)(kt0 + ln) * HD + hi * 8;
  // V^T as A-frag: row=d=ln, k = 8*hi + j
  const ushort* Vp = Vh + (size_t)ln * S + kt0 + hi * 8;

  bf16x8 kf0 = *(const bf16x8*)&Kp[0];
  bf16x8 kf1 = *(const bf16x8*)&Kp[16];
  bf16x8 kf2 = *(const bf16x8*)&Kp[32 * HD];
  bf16x8 kf3 = *(const bf16x8*)&Kp[32 * HD + 16];

  #pragma unroll 1
  for (int it = 0; it < S / KSPLIT / 64; ++it) {
    bf16x8 vf0 = *(const bf16x8*)&Vp[0];
    bf16x8 vf1 = *(const bf16x8*)&Vp[16];
    bf16x8 vf2 = *(const bf16x8*)&Vp[32];
    bf16x8 vf3 = *(const bf16x8*)&Vp[48];
    Vp += 64;
    Kp += 64 * HD;

    // keys kt..kt+31
    f32x16 s = __builtin_amdgcn_mfma_f32_32x32x16_bf16(kf0, qf0, z, 0, 0, 0);
    s = __builtin_amdgcn_mfma_f32_32x32x16_bf16(kf1, qf1, s, 0, 0, 0);
    // prefetch next tile's lo-key frags (overread stays inside the workspace)
    kf0 = *(const bf16x8*)&Kp[0];
    kf1 = *(const bf16x8*)&Kp[16];
    bf16x8 pf0, pf1;
    s_to_pf(s, pf0, pf1, lacc);
    acc = __builtin_amdgcn_mfma_f32_32x32x16_bf16(vf0, pf0, acc, 0, 0, 0);
    acc = __builtin_amdgcn_mfma_f32_32x32x16_bf16(vf1, pf1, acc, 0, 0, 0);

    // keys kt+32..kt+63
    f32x16 t = __builtin_amdgcn_mfma_f32_32x32x16_bf16(kf2, qf0, z, 0, 0, 0);
    t = __builtin_amdgcn_mfma_f32_32x32x16_bf16(kf3, qf1, t, 0, 0, 0);
    kf2 = *(const bf16x8*)&Kp[32 * HD];
    kf3 = *(const bf16x8*)&Kp[32 * HD + 16];
    bf16x8 pf2, pf3;
    s_to_pf(t, pf2, pf3, lacc);
    acc = __builtin_amdgcn_mfma_f32_32x32x16_bf16(vf2, pf2, acc, 0, 0, 0);
    acc = __builtin_amdgcn_mfma_f32_32x32x16_bf16(vf3, pf3, acc, 0, 0, 0);
  }

  // acc[r]: d = (r&3) + 8*(r>>2) + 4*hi, q = ln
  float* ap = accP + ((size_t)((kp * 2 + b) * NH + h)) * S * HD;
  const size_t qrow = (size_t)(q0 + ln) * HD;
  #pragma unroll
  for (int g = 0; g < 4; g++) {
    float4 u;
    u.x = acc[4 * g + 0];
    u.y = acc[4 * g + 1];
    u.z = acc[4 * g + 2];
    u.w = acc[4 * g + 3];
    *(float4*)&ap[qrow + g * 8 + hi * 4] = u;
  }
  const float lsum = lacc + __shfl_xor(lacc, 32, 64);
  if (hi == 0)
    lP[((size_t)((kp * 2 + b) * NH + h)) * S + q0 + ln] = lsum;
}

// ---------------- combine K-split partials -> Yt [b][s][256] bf16 ------------
__global__ __launch_bounds__(256) void combine_kernel(const float* __restrict__ accP,
                                                      const float* __restrict__ lP,
                                                      ushort* __restrict__ Yt) {
  const int tid = blockIdx.x * 256 + threadIdx.x;
  const int dg = tid & 7;
  const int q = (tid >> 3) & (S - 1);
  const int h = (tid >> 15) & 7;
  const int b = tid >> 18;
  const size_t i0 = ((size_t)(b * NH + h)) * S + q;
  const size_t part = (size_t)2 * NH * S;
  float sx = 0.f, sy = 0.f, sz = 0.f, sw = 0.f, L = 0.f;
  #pragma unroll
  for (int p = 0; p < KSPLIT; p++) {
    const float4 a = *(const float4*)&accP[(size_t)p * part * HD + i0 * HD + dg * 4];
    sx += a.x; sy += a.y; sz += a.z; sw += a.w;
    L += lP[(size_t)p * part + i0];
  }
  const float rl = 1.0f / L;
  ushort4 o;
  o.x = f2bf(sx * rl);
  o.y = f2bf(sy * rl);
  o.z = f2bf(sz * rl);
  o.w = f2bf(sw * rl);
  *(ushort4*)&Yt[((size_t)b * S + q) * CIN + h * HD + dg * 4] = o;
}

// ---------------- conv2: OUT[b][m][s] fp32 = Wo . Yt, fused mp_add -----------
__global__ __launch_bounds__(256) void conv2_kernel(const ushort* __restrict__ W,
                                                    const ushort* __restrict__ Bm,
                                                    const float* __restrict__ RES,
                                                    float* __restrict__ OUT) {
  const int b = blockIdx.z;
  const int wid = threadIdx.x >> 6, lane = threadIdx.x & 63;
  const int col = lane & 15, quad = lane >> 4;
  const int m0 = blockIdx.y * 64 + (wid >> 1) * 32;
  const int n0 = blockIdx.x * 128 + (wid & 1) * 64;
  const ushort* Bb = Bm + (size_t)b * S * CIN;
  f32x4 acc[2][4] = {};
  #pragma unroll
  for (int k0 = 0; k0 < CIN; k0 += 32) {
    bf16x8 af[2], bf[4];
    #pragma unroll
    for (int mi = 0; mi < 2; mi++)
      af[mi] = *(const bf16x8*)&W[(size_t)(m0 + mi * 16 + col) * CIN + k0 + quad * 8];
    #pragma unroll
    for (int ni = 0; ni < 4; ni++)
      bf[ni] = *(const bf16x8*)&Bb[(size_t)(n0 + ni * 16 + col) * CIN + k0 + quad * 8];
    #pragma unroll
    for (int mi = 0; mi < 2; mi++)
      #pragma unroll
      for (int ni = 0; ni < 4; ni++)
        acc[mi][ni] = __builtin_amdgcn_mfma_f32_16x16x32_bf16(af[mi], bf[ni], acc[mi][ni], 0, 0, 0);
  }
  const float tc = 0.3f, om = 0.7f, inv = 1.3130643285972254f;
  #pragma unroll
  for (int mi = 0; mi < 2; mi++)
    #pragma unroll
    for (int ni = 0; ni < 4; ni++)
      #pragma unroll
      for (int r = 0; r < 4; r++) {
        const size_t idx = ((size_t)(b * CIN + m0 + mi * 16 + quad * 4 + r)) * S + n0 + ni * 16 + col;
        OUT[idx] = (om * RES[idx] + tc * acc[mi][ni][r]) * inv;
      }
}

// ---------------- launch ----------------
extern "C" void kernel_launch(void* const* d_in, const int* in_sizes, int n_in,
                              void* d_out, int out_size, void* d_ws, size_t ws_size,
                              hipStream_t stream) {
  const float* x = (const float*)d_in[0];
  const float* w_qkv = (const float*)d_in[1];
  const float* w_out = (const float*)d_in[2];
  float* out = (float*)d_out;

  ushort* p = (ushort*)d_ws;
  ushort* wqb = p; p += (size_t)C3 * CIN;
  ushort* wob = p; p += (size_t)CIN * CIN;
  ushort* Qn = p; p += (size_t)2 * NH * S * HD;
  ushort* Kn = p; p += (size_t)2 * NH * S * HD;
  ushort* Vt = p; p += (size_t)2 * NH * S * HD;
  ushort* Yt = p; p += (size_t)2 * S * CIN;
  // Region R: Xt (4.2 MB bf16) dies after conv1_fused; accP fp32
  // (KSPLIT*2*8*4096*32 floats = 33.5 MB) aliases the same region.
  ushort* R = p; p += (size_t)KSPLIT * 2 * NH * S * HD * 2;  // 33.5 MB
  ushort* Xt = R;
  float* accP = (float*)R;
  float* lP = (float*)p;  // KSPLIT*2*8*4096 floats = 1 MB

  wnorm_kernel<<<(C3 + CIN) / 4, 256, 0, stream>>>(w_qkv, w_out, wqb, wob);
  xt_kernel<<<dim3(S / 64, CIN / 64, 2), 256, 0, stream>>>(x, Xt);
  conv1_fused_kernel<<<dim3(S / 128, C3 / 64, 2), 256, 0, stream>>>(wqb, Xt, Qn, Kn, Vt);
  attn_kernel<<<(S / 128) * NH * KSPLIT * 2, 256, 0, stream>>>(Qn, Kn, Vt, accP, lP);
  combine_kernel<<<2048, 256, 0, stream>>>(accP, lP, Yt);
  conv2_kernel<<<dim3(S / 128, CIN / 64, 2), 256, 0, stream>>>(wob, Yt, x, out);
}

// Round 3
// 163.174 us; speedup vs baseline: 1.5129x; 1.5129x over previous
//
#include <hip/hip_runtime.h>
#include <hip/hip_bf16.h>
#include <math.h>

#define S 4096
#define CIN 256
#define C3 768
#define NH 8
#define HD 32
#define KSPLIT 2

static constexpr float EPS = 1e-4f;

typedef __attribute__((ext_vector_type(8))) __bf16 bf16x8;
typedef __attribute__((ext_vector_type(4))) float f32x4;
typedef __attribute__((ext_vector_type(16))) float f32x16;
typedef __attribute__((ext_vector_type(8))) unsigned short u16x8;
typedef __attribute__((ext_vector_type(4))) unsigned u32x4;

static inline __device__ ushort f2bf(float f) {  // RN-even
  unsigned u = __float_as_uint(f);
  return (ushort)((u + 0x7fffu + ((u >> 16) & 1u)) >> 16);
}

// v_cvt_pk_bf16_f32: dst.lo16 = bf16(lo), dst.hi16 = bf16(hi); RNE (no builtin)
static inline __device__ unsigned cvt_pk_bf16(float lo, float hi) {
  unsigned r;
  asm("v_cvt_pk_bf16_f32 %0, %1, %2" : "=v"(r) : "v"(lo), "v"(hi));
  return r;
}
// v_permlane32_swap_b32: a.hi32lanes <-> b.lo32lanes.
static inline __device__ void plane32_swap(unsigned& a, unsigned& b) {
  asm("v_permlane32_swap_b32 %0, %1" : "+v"(a), "+v"(b));
}

#define EXP2 __builtin_amdgcn_exp2f

// Convert one 32x32 QK score tile (D-layout: col=q=lane&31, row=k=(r&3)+8*(r>>2)+4*hi)
// to two PV operand fragments (col/row=q, k = frag*8 elements at 8*hi+j) fully
// in registers: 8 cvt_pk + 4 permlane32_swap. plo covers k 0..15, phi 16..31.
static inline __device__ void s_to_pf(const f32x16 s, bf16x8& plo, bf16x8& phi) {
  unsigned c0 = cvt_pk_bf16(EXP2(s[0]), EXP2(s[1]));    // hi0:k(0,1)   hi1:k(4,5)
  unsigned c1 = cvt_pk_bf16(EXP2(s[2]), EXP2(s[3]));    // hi0:k(2,3)   hi1:k(6,7)
  unsigned c2 = cvt_pk_bf16(EXP2(s[4]), EXP2(s[5]));    // hi0:k(8,9)   hi1:k(12,13)
  unsigned c3 = cvt_pk_bf16(EXP2(s[6]), EXP2(s[7]));    // hi0:k(10,11) hi1:k(14,15)
  plane32_swap(c0, c2);
  plane32_swap(c1, c3);
  u32x4 lo4 = {c0, c1, c2, c3};
  plo = __builtin_bit_cast(bf16x8, lo4);
  unsigned c4 = cvt_pk_bf16(EXP2(s[8]), EXP2(s[9]));
  unsigned c5 = cvt_pk_bf16(EXP2(s[10]), EXP2(s[11]));
  unsigned c6 = cvt_pk_bf16(EXP2(s[12]), EXP2(s[13]));
  unsigned c7 = cvt_pk_bf16(EXP2(s[14]), EXP2(s[15]));
  plane32_swap(c4, c6);
  plane32_swap(c5, c7);
  u32x4 hi4 = {c4, c5, c6, c7};
  phi = __builtin_bit_cast(bf16x8, hi4);
}

// ---------------- weight norm (both weights, one launch) ---------------------
__global__ __launch_bounds__(256) void wnorm_kernel(const float* __restrict__ w_qkv,
                                                    const float* __restrict__ w_out,
                                                    ushort* __restrict__ wqb,
                                                    ushort* __restrict__ wob) {
  const int row = blockIdx.x * 4 + (threadIdx.x >> 6);
  const int lane = threadIdx.x & 63;
  const bool is_q = row < C3;
  const float* wr = (is_q ? w_qkv + (size_t)row * CIN : w_out + (size_t)(row - C3) * CIN);
  float v0 = wr[lane], v1 = wr[lane + 64], v2 = wr[lane + 128], v3 = wr[lane + 192];
  float ss = v0 * v0 + v1 * v1 + v2 * v2 + v3 * v3;
  #pragma unroll
  for (int off = 32; off > 0; off >>= 1) ss += __shfl_down(ss, off, 64);
  ss = __shfl(ss, 0, 64);
  const float scale = 1.0f / (sqrtf(ss) + 16.0f * EPS);
  ushort* whr = (is_q ? wqb + (size_t)row * CIN : wob + (size_t)(row - C3) * CIN);
  whr[lane] = f2bf(v0 * scale);
  whr[lane + 64] = f2bf(v1 * scale);
  whr[lane + 128] = f2bf(v2 * scale);
  whr[lane + 192] = f2bf(v3 * scale);
}

// ---------------- X [b][c][s] fp32 -> Xt [b][s][c] bf16 ----------------------
__global__ __launch_bounds__(256) void xt_kernel(const float* __restrict__ X,
                                                 ushort* __restrict__ Xt) {
  const int b = blockIdx.z;
  const int s0 = blockIdx.x * 64, c0 = blockIdx.y * 64;
  __shared__ ushort T[64][72];
  const int tc = threadIdx.x >> 4;
  const int ts = threadIdx.x & 15;
  #pragma unroll
  for (int i = 0; i < 4; i++) {
    const float4 v = *(const float4*)&X[((size_t)(b * CIN + c0 + tc + 16 * i)) * S + s0 + ts * 4];
    ushort4 u;
    u.x = f2bf(v.x); u.y = f2bf(v.y); u.z = f2bf(v.z); u.w = f2bf(v.w);
    *(ushort4*)&T[tc + 16 * i][ts * 4] = u;
  }
  __syncthreads();
  #pragma unroll
  for (int i = 0; i < 4; i++) {
    const int sr = tc + 16 * i;
    ushort4 u;
    u.x = T[ts * 4 + 0][sr];
    u.y = T[ts * 4 + 1][sr];
    u.z = T[ts * 4 + 2][sr];
    u.w = T[ts * 4 + 3][sr];
    *(ushort4*)&Xt[((size_t)b * S + s0 + sr) * CIN + c0 + ts * 4] = u;
  }
}

// ---------------- conv1 fused with pixel-norm + layout fan-out ---------------
// Q written as [bh][q][HD] rows (loaded once per attn wave). K and V written in
// MFMA-FRAGMENT-ORDERED PANELS so every attn fragment load is base + lane*16B
// (dense 1KB/instruction, 8 cache lines instead of 32-64):
//   Kpan: [bh][key>>5][half][key&31][hi][8]  (half = ch/16, hi = (ch&15)>>3)
//   Vpan: [bh][key>>6][kc][d][hi][8]         (kc = (key&63)>>4, hi = (key&15)>>3)
__global__ __launch_bounds__(256) void conv1_fused_kernel(const ushort* __restrict__ W,
                                                          const ushort* __restrict__ Bm,
                                                          ushort* __restrict__ Qn,
                                                          ushort* __restrict__ Kn,
                                                          ushort* __restrict__ Vt) {
  const int b = blockIdx.z;
  const int wid = threadIdx.x >> 6, lane = threadIdx.x & 63;
  const int col = lane & 15, quad = lane >> 4;
  const int m0 = blockIdx.y * 64 + (wid >> 1) * 32;  // 32-aligned: one head group
  const int n0 = blockIdx.x * 128 + (wid & 1) * 64;
  const ushort* Bb = Bm + (size_t)b * S * CIN;
  f32x4 acc[2][4] = {};
  #pragma unroll
  for (int k0 = 0; k0 < CIN; k0 += 32) {
    bf16x8 af[2], bf[4];
    #pragma unroll
    for (int mi = 0; mi < 2; mi++)
      af[mi] = *(const bf16x8*)&W[(size_t)(m0 + mi * 16 + col) * CIN + k0 + quad * 8];
    #pragma unroll
    for (int ni = 0; ni < 4; ni++)
      bf[ni] = *(const bf16x8*)&Bb[(size_t)(n0 + ni * 16 + col) * CIN + k0 + quad * 8];
    #pragma unroll
    for (int mi = 0; mi < 2; mi++)
      #pragma unroll
      for (int ni = 0; ni < 4; ni++)
        acc[mi][ni] = __builtin_amdgcn_mfma_f32_16x16x32_bf16(af[mi], bf[ni], acc[mi][ni], 0, 0, 0);
  }

  const int g = m0 >> 5;   // 0..23: group; 0-7 Q, 8-15 K, 16-23 V
  const int h = g & 7;
  float rn[4];
  #pragma unroll
  for (int ni = 0; ni < 4; ni++) {
    float ss = 0.f;
    #pragma unroll
    for (int mi = 0; mi < 2; mi++)
      #pragma unroll
      for (int r = 0; r < 4; r++) ss += acc[mi][ni][r] * acc[mi][ni][r];
    ss += __shfl_xor(ss, 16, 64);
    ss += __shfl_xor(ss, 32, 64);
    rn[ni] = rsqrtf(ss * (1.0f / HD) + EPS);
    if (g < 8) rn[ni] *= 0.2550348190698169f;  // log2(e)/sqrt(32) folded into Q
  }

  if (g < 8) {  // Q: row layout [q][HD]
    ushort* dst = Qn + (size_t)(b * NH + h) * S * HD;
    #pragma unroll
    for (int mi = 0; mi < 2; mi++)
      #pragma unroll
      for (int ni = 0; ni < 4; ni++) {
        ushort4 u;
        u.x = f2bf(acc[mi][ni][0] * rn[ni]);
        u.y = f2bf(acc[mi][ni][1] * rn[ni]);
        u.z = f2bf(acc[mi][ni][2] * rn[ni]);
        u.w = f2bf(acc[mi][ni][3] * rn[ni]);
        *(ushort4*)&dst[(size_t)(n0 + ni * 16 + col) * HD + mi * 16 + quad * 4] = u;
      }
  } else if (g < 16) {  // K: fragment panels
    // key = n0 + ni*16 + col; ch = mi*16 + quad*4 + r
    ushort* dst = Kn + (size_t)(b * NH + h) * S * HD + (size_t)(n0 >> 5) * 1024;
    #pragma unroll
    for (int mi = 0; mi < 2; mi++)
      #pragma unroll
      for (int ni = 0; ni < 4; ni++) {
        ushort4 u;
        u.x = f2bf(acc[mi][ni][0] * rn[ni]);
        u.y = f2bf(acc[mi][ni][1] * rn[ni]);
        u.z = f2bf(acc[mi][ni][2] * rn[ni]);
        u.w = f2bf(acc[mi][ni][3] * rn[ni]);
        *(ushort4*)&dst[(ni >> 1) * 1024 + mi * 512 + ((ni & 1) * 16 + col) * 16 +
                        (quad >> 1) * 8 + (quad & 1) * 4] = u;
      }
  } else {  // V: fragment panels (d = mi*16+quad*4+r, key = n0+ni*16+col)
    ushort* dst = Vt + (size_t)(b * NH + h) * HD * S + (size_t)(n0 >> 6) * 2048;
    #pragma unroll
    for (int mi = 0; mi < 2; mi++)
      #pragma unroll
      for (int ni = 0; ni < 4; ni++)
        #pragma unroll
        for (int r = 0; r < 4; r++)
          dst[ni * 512 + (mi * 16 + quad * 4 + r) * 16 + col] =
              f2bf(acc[mi][ni][r] * rn[ni]);
  }
}

// ---------------- MFMA attention: 32x32 tiles, P in registers ----------------
// S^T = K.Q^T via mfma_32x32x16 (Q pre-scaled -> exp2 direct). P rebuilt into
// the PV operand fragment in registers (T12). K/V read from fragment-ordered
// panels: every load is base + lane*16B (dense 1KB). K AND V prefetched one
// 64-key tile ahead. l via ones-MFMA (on the idle MFMA pipe). Zero LDS.
// Bijective XCD swizzle: each XCD owns 4 complete (b,kp,h) groups -> K/V
// working set ~1MB, L2-resident. grid 1024 x 256 (4 waves), 4 blocks/CU.
__global__ __launch_bounds__(256, 4) void attn_kernel(const ushort* __restrict__ Qn,
                                                      const ushort* __restrict__ Kn,
                                                      const ushort* __restrict__ Vt,
                                                      float* __restrict__ accP,
                                                      float* __restrict__ lP) {
  const int bid = blockIdx.x;
  const int id = (bid & 7) * (1024 / 8) + (bid >> 3);  // XCD = bid&7 gets 128 consecutive ids
  const int qt = id & 31;
  const int grp = id >> 5;      // 0..31 = ((b*KSPLIT + kp) << 3) | h
  const int h = grp & 7;
  const int kp = (grp >> 3) & (KSPLIT - 1);
  const int b = grp >> 4;
  const int wid = threadIdx.x >> 6, lane = threadIdx.x & 63;
  const int ln = lane & 31, hi = lane >> 5;
  const int q0 = qt * 128 + wid * 32;

  const ushort* Qh = Qn + (size_t)(b * NH + h) * S * HD;

  // Q as B-frag: col=q=ln, ch = half*16 + 8*hi + j
  bf16x8 qf0 = *(const bf16x8*)&Qh[(size_t)(q0 + ln) * HD + hi * 8];
  bf16x8 qf1 = *(const bf16x8*)&Qh[(size_t)(q0 + ln) * HD + 16 + hi * 8];

  const u16x8 ou = {0x3F80, 0x3F80, 0x3F80, 0x3F80, 0x3F80, 0x3F80, 0x3F80, 0x3F80};
  const bf16x8 ones = __builtin_bit_cast(bf16x8, ou);
  const f32x16 z = {};
  f32x16 acc = {};   // out^T tile: row=d, col=q
  f32x16 accl = {};  // softmax denom (all rows identical)

  const int kt0 = kp * (S / KSPLIT);
  // fragment-panel bases; every frag load = base + frag_offset + loff
  const int loff = ((lane & 31) * 2 + (lane >> 5)) * 8;
  const ushort* Kp = Kn + (size_t)(b * NH + h) * S * HD + (size_t)kt0 * 32 + loff;
  const ushort* Vp = Vt + (size_t)(b * NH + h) * HD * S + (size_t)kt0 * 32 + loff;

  bf16x8 kf0 = *(const bf16x8*)&Kp[0];
  bf16x8 kf1 = *(const bf16x8*)&Kp[512];
  bf16x8 kf2 = *(const bf16x8*)&Kp[1024];
  bf16x8 kf3 = *(const bf16x8*)&Kp[1536];
  bf16x8 vf0 = *(const bf16x8*)&Vp[0];
  bf16x8 vf1 = *(const bf16x8*)&Vp[512];
  bf16x8 vf2 = *(const bf16x8*)&Vp[1024];
  bf16x8 vf3 = *(const bf16x8*)&Vp[1536];

  #pragma unroll 1
  for (int it = 0; it < S / KSPLIT / 64; ++it) {
    Kp += 2048;
    Vp += 2048;

    // keys +0..31
    f32x16 s = __builtin_amdgcn_mfma_f32_32x32x16_bf16(kf0, qf0, z, 0, 0, 0);
    s = __builtin_amdgcn_mfma_f32_32x32x16_bf16(kf1, qf1, s, 0, 0, 0);
    kf0 = *(const bf16x8*)&Kp[0];       // prefetch next tile (overread stays in workspace)
    kf1 = *(const bf16x8*)&Kp[512];
    bf16x8 pf0, pf1;
    s_to_pf(s, pf0, pf1);
    acc = __builtin_amdgcn_mfma_f32_32x32x16_bf16(vf0, pf0, acc, 0, 0, 0);
    accl = __builtin_amdgcn_mfma_f32_32x32x16_bf16(ones, pf0, accl, 0, 0, 0);
    acc = __builtin_amdgcn_mfma_f32_32x32x16_bf16(vf1, pf1, acc, 0, 0, 0);
    accl = __builtin_amdgcn_mfma_f32_32x32x16_bf16(ones, pf1, accl, 0, 0, 0);

    // keys +32..63
    f32x16 t = __builtin_amdgcn_mfma_f32_32x32x16_bf16(kf2, qf0, z, 0, 0, 0);
    t = __builtin_amdgcn_mfma_f32_32x32x16_bf16(kf3, qf1, t, 0, 0, 0);
    kf2 = *(const bf16x8*)&Kp[1024];
    kf3 = *(const bf16x8*)&Kp[1536];
    bf16x8 pf2, pf3;
    s_to_pf(t, pf2, pf3);
    acc = __builtin_amdgcn_mfma_f32_32x32x16_bf16(vf2, pf2, acc, 0, 0, 0);
    accl = __builtin_amdgcn_mfma_f32_32x32x16_bf16(ones, pf2, accl, 0, 0, 0);
    acc = __builtin_amdgcn_mfma_f32_32x32x16_bf16(vf3, pf3, acc, 0, 0, 0);
    accl = __builtin_amdgcn_mfma_f32_32x32x16_bf16(ones, pf3, accl, 0, 0, 0);

    vf0 = *(const bf16x8*)&Vp[0];       // prefetch next tile's V (consumed mid-next-iter)
    vf1 = *(const bf16x8*)&Vp[512];
    vf2 = *(const bf16x8*)&Vp[1024];
    vf3 = *(const bf16x8*)&Vp[1536];
  }

  // acc[r]: d = (r&3) + 8*(r>>2) + 4*hi, q = ln
  float* ap = accP + ((size_t)((kp * 2 + b) * NH + h)) * S * HD;
  const size_t qrow = (size_t)(q0 + ln) * HD;
  #pragma unroll
  for (int g = 0; g < 4; g++) {
    float4 u;
    u.x = acc[4 * g + 0];
    u.y = acc[4 * g + 1];
    u.z = acc[4 * g + 2];
    u.w = acc[4 * g + 3];
    *(float4*)&ap[qrow + g * 8 + hi * 4] = u;
  }
  if (hi == 0)
    lP[((size_t)((kp * 2 + b) * NH + h)) * S + q0 + ln] = accl[0];
}

// ---------------- combine K-split partials -> Yt [b][s][256] bf16 ------------
__global__ __launch_bounds__(256) void combine_kernel(const float* __restrict__ accP,
                                                      const float* __restrict__ lP,
                                                      ushort* __restrict__ Yt) {
  const int tid = blockIdx.x * 256 + threadIdx.x;
  const int dg = tid & 7;
  const int q = (tid >> 3) & (S - 1);
  const int h = (tid >> 15) & 7;
  const int b = tid >> 18;
  const size_t i0 = ((size_t)(b * NH + h)) * S + q;
  const size_t part = (size_t)2 * NH * S;
  float sx = 0.f, sy = 0.f, sz = 0.f, sw = 0.f, L = 0.f;
  #pragma unroll
  for (int p = 0; p < KSPLIT; p++) {
    const float4 a = *(const float4*)&accP[(size_t)p * part * HD + i0 * HD + dg * 4];
    sx += a.x; sy += a.y; sz += a.z; sw += a.w;
    L += lP[(size_t)p * part + i0];
  }
  const float rl = 1.0f / L;
  ushort4 o;
  o.x = f2bf(sx * rl);
  o.y = f2bf(sy * rl);
  o.z = f2bf(sz * rl);
  o.w = f2bf(sw * rl);
  *(ushort4*)&Yt[((size_t)b * S + q) * CIN + h * HD + dg * 4] = o;
}

// ---------------- conv2: OUT[b][m][s] fp32 = Wo . Yt, fused mp_add -----------
__global__ __launch_bounds__(256) void conv2_kernel(const ushort* __restrict__ W,
                                                    const ushort* __restrict__ Bm,
                                                    const float* __restrict__ RES,
                                                    float* __restrict__ OUT) {
  const int b = blockIdx.z;
  const int wid = threadIdx.x >> 6, lane = threadIdx.x & 63;
  const int col = lane & 15, quad = lane >> 4;
  const int m0 = blockIdx.y * 64 + (wid >> 1) * 32;
  const int n0 = blockIdx.x * 128 + (wid & 1) * 64;
  const ushort* Bb = Bm + (size_t)b * S * CIN;
  f32x4 acc[2][4] = {};
  #pragma unroll
  for (int k0 = 0; k0 < CIN; k0 += 32) {
    bf16x8 af[2], bf[4];
    #pragma unroll
    for (int mi = 0; mi < 2; mi++)
      af[mi] = *(const bf16x8*)&W[(size_t)(m0 + mi * 16 + col) * CIN + k0 + quad * 8];
    #pragma unroll
    for (int ni = 0; ni < 4; ni++)
      bf[ni] = *(const bf16x8*)&Bb[(size_t)(n0 + ni * 16 + col) * CIN + k0 + quad * 8];
    #pragma unroll
    for (int mi = 0; mi < 2; mi++)
      #pragma unroll
      for (int ni = 0; ni < 4; ni++)
        acc[mi][ni] = __builtin_amdgcn_mfma_f32_16x16x32_bf16(af[mi], bf[ni], acc[mi][ni], 0, 0, 0);
  }
  const float tc = 0.3f, om = 0.7f, inv = 1.3130643285972254f;
  #pragma unroll
  for (int mi = 0; mi < 2; mi++)
    #pragma unroll
    for (int ni = 0; ni < 4; ni++)
      #pragma unroll
      for (int r = 0; r < 4; r++) {
        const size_t idx = ((size_t)(b * CIN + m0 + mi * 16 + quad * 4 + r)) * S + n0 + ni * 16 + col;
        OUT[idx] = (om * RES[idx] + tc * acc[mi][ni][r]) * inv;
      }
}

// ---------------- launch ----------------
extern "C" void kernel_launch(void* const* d_in, const int* in_sizes, int n_in,
                              void* d_out, int out_size, void* d_ws, size_t ws_size,
                              hipStream_t stream) {
  const float* x = (const float*)d_in[0];
  const float* w_qkv = (const float*)d_in[1];
  const float* w_out = (const float*)d_in[2];
  float* out = (float*)d_out;

  ushort* p = (ushort*)d_ws;
  ushort* wqb = p; p += (size_t)C3 * CIN;
  ushort* wob = p; p += (size_t)CIN * CIN;
  ushort* Qn = p; p += (size_t)2 * NH * S * HD;
  ushort* Kn = p; p += (size_t)2 * NH * S * HD;
  ushort* Vt = p; p += (size_t)2 * NH * S * HD;
  ushort* Yt = p; p += (size_t)2 * S * CIN;
  // Region R: Xt (4.2 MB bf16) dies after conv1_fused; accP fp32
  // (KSPLIT*2*8*4096*32 floats = 16.78 MB) aliases the same region.
  ushort* R = p; p += (size_t)KSPLIT * 2 * NH * S * HD * 2;  // 16.78 MB
  ushort* Xt = R;
  float* accP = (float*)R;
  float* lP = (float*)p;  // KSPLIT*2*8*4096 floats = 0.5 MB

  wnorm_kernel<<<(C3 + CIN) / 4, 256, 0, stream>>>(w_qkv, w_out, wqb, wob);
  xt_kernel<<<dim3(S / 64, CIN / 64, 2), 256, 0, stream>>>(x, Xt);
  conv1_fused_kernel<<<dim3(S / 128, C3 / 64, 2), 256, 0, stream>>>(wqb, Xt, Qn, Kn, Vt);
  attn_kernel<<<(S / 128) * NH * KSPLIT * 2, 256, 0, stream>>>(Qn, Kn, Vt, accP, lP);
  combine_kernel<<<2048, 256, 0, stream>>>(accP, lP, Yt);
  conv2_kernel<<<dim3(S / 128, CIN / 64, 2), 256, 0, stream>>>(wob, Yt, x, out);
}